// Round 5
// baseline (2665.606 us; speedup 1.0000x reference)
//
#include <hip/hip_runtime.h>
#include <hip/hip_bf16.h>

#define VOCAB 32000
#define EMB   128
#define HID   128
#define BB    8
#define SS    1024

typedef __bf16 bf16x8_t __attribute__((ext_vector_type(8)));
typedef float  f32x4_t  __attribute__((ext_vector_type(4)));

// ---------------------------------------------------------------------------
// Kernel A: xp[b,s,h] = sum_e emb[x[b,s],e] * W_ih[h,e] + b_ih[h] + b_hh[h]
// ---------------------------------------------------------------------------
__global__ __launch_bounds__(512) void xproj_kernel(
    const int* __restrict__ x, const float* __restrict__ emb,
    const float* __restrict__ W_ih, const float* __restrict__ b_ih,
    const float* __restrict__ b_hh, float* __restrict__ xp)
{
    const int t  = threadIdx.x;
    const int h  = t >> 2;
    const int ks = t & 3;

    float w[32];
    {
        const float* wr = W_ih + h * EMB + ks * 32;
        #pragma unroll
        for (int i = 0; i < 32; i += 4) {
            float4 v = *(const float4*)(wr + i);
            w[i] = v.x; w[i+1] = v.y; w[i+2] = v.z; w[i+3] = v.w;
        }
    }
    const float bias = b_ih[h] + b_hh[h];

    __shared__ float el[2][EMB];
    const int base = blockIdx.x * 32;

    float4 v = make_float4(0.f, 0.f, 0.f, 0.f);
    if (t < 32) v = *(const float4*)(emb + (size_t)x[base] * EMB + t * 4);

    for (int r = 0; r < 32; ++r) {
        if (t < 32) *(float4*)(&el[r & 1][t * 4]) = v;
        __syncthreads();
        if (t < 32 && r + 1 < 32)
            v = *(const float4*)(emb + (size_t)x[base + r + 1] * EMB + t * 4);

        float a0 = 0.f, a1 = 0.f, a2 = 0.f, a3 = 0.f;
        const float* e = &el[r & 1][ks * 32];
        #pragma unroll
        for (int c = 0; c < 8; ++c) {
            float4 hv = *(const float4*)(e + c * 4);
            a0 = fmaf(w[c*4+0], hv.x, a0);
            a1 = fmaf(w[c*4+1], hv.y, a1);
            a2 = fmaf(w[c*4+2], hv.z, a2);
            a3 = fmaf(w[c*4+3], hv.w, a3);
        }
        float sum = (a0 + a1) + (a2 + a3);
        sum += __shfl_xor(sum, 1);
        sum += __shfl_xor(sum, 2);
        if (ks == 0) xp[(size_t)(base + r) * HID + h] = bias + sum;
    }
}

// ---------------------------------------------------------------------------
// Kernel D: fp32 -> bf16 convert for fc_W
// ---------------------------------------------------------------------------
__global__ __launch_bounds__(256) void convert_bf16_kernel(
    const float* __restrict__ in, __hip_bfloat16* __restrict__ out)
{
    const size_t i = ((size_t)blockIdx.x * 256 + threadIdx.x) * 8;
    float4 a = *(const float4*)(in + i);
    float4 b = *(const float4*)(in + i + 4);
    union { __hip_bfloat16 h[8]; uint4 u; } p;
    p.h[0] = __float2bfloat16(a.x); p.h[1] = __float2bfloat16(a.y);
    p.h[2] = __float2bfloat16(a.z); p.h[3] = __float2bfloat16(a.w);
    p.h[4] = __float2bfloat16(b.x); p.h[5] = __float2bfloat16(b.y);
    p.h[6] = __float2bfloat16(b.z); p.h[7] = __float2bfloat16(b.w);
    *(uint4*)(out + i) = p.u;
}

// ---------------------------------------------------------------------------
// Kernel B: recurrence, REP=4 instrumentation (idempotent: full restart from
// h=0 each rep; same bytes written each rep).
// ---------------------------------------------------------------------------
__global__ __launch_bounds__(512) void rnn_kernel(
    const float* __restrict__ xp, const float* __restrict__ W_hh,
    __hip_bfloat16* __restrict__ hs_bf16, float* __restrict__ hidden_out)
{
    const int b  = blockIdx.x;
    const int t  = threadIdx.x;
    const int j  = t >> 2;
    const int ks = t & 3;

    float w[32];
    {
        const float* wr = W_hh + j * HID + ks * 32;
        #pragma unroll
        for (int i = 0; i < 32; i += 4) {
            float4 v = *(const float4*)(wr + i);
            w[i] = v.x; w[i+1] = v.y; w[i+2] = v.z; w[i+3] = v.w;
        }
    }

    __shared__ float hbuf[2][HID];
    const float* xpb = xp + (size_t)b * SS * HID;

    for (int rep = 0; rep < 4; ++rep) {
        if (t < HID) hbuf[0][t] = 0.f;
        float xp0 = xpb[j];
        float xp1 = xpb[HID + j];
        __syncthreads();

        for (int step = 0; step < SS; ++step) {
            const float* hc = &hbuf[step & 1][ks * 32];
            float a0 = 0.f, a1 = 0.f, a2 = 0.f, a3 = 0.f;
            #pragma unroll
            for (int c = 0; c < 8; ++c) {
                float4 hv = *(const float4*)(hc + c * 4);
                a0 = fmaf(w[c*4+0], hv.x, a0);
                a1 = fmaf(w[c*4+1], hv.y, a1);
                a2 = fmaf(w[c*4+2], hv.z, a2);
                a3 = fmaf(w[c*4+3], hv.w, a3);
            }
            float sum = (a0 + a1) + (a2 + a3);
            sum += __shfl_xor(sum, 1);
            sum += __shfl_xor(sum, 2);

            const float xpt = xp0;
            xp0 = xp1;
            if (step + 2 < SS) xp1 = xpb[(size_t)(step + 2) * HID + j];

            float z  = xpt + sum;
            float e  = __expf(2.0f * z);
            float hn = 1.0f - 2.0f * __builtin_amdgcn_rcpf(e + 1.0f);

            if (ks == 0) hbuf[(step + 1) & 1][j] = hn;
            if (ks == 1) hs_bf16[((size_t)b * SS + step) * HID + j] = __float2bfloat16(hn);
            if (ks == 2 && step == SS - 1) hidden_out[b * HID + j] = hn;
            __syncthreads();
        }
        asm volatile("" ::: "memory");
    }
}

// ---------------------------------------------------------------------------
// Kernel C: logits = A @ Wb^T + fc_b.  REP=4 instrumentation.
// Swapped-operand MFMA (reg axis = vocab cols -> float4 stores), NORMAL
// stores (via L2 -> full-line assembly), XCD-chunked swizzle with nb FAST
// (concurrent blocks extend the same rows -> contiguous DRAM write streams).
// ---------------------------------------------------------------------------
__global__ __launch_bounds__(256) void fc_kernel(
    const __hip_bfloat16* __restrict__ A, const __hip_bfloat16* __restrict__ Wb,
    const float* __restrict__ fc_b, float* __restrict__ C)
{
    const int lane = threadIdx.x & 63;
    const int wv   = threadIdx.x >> 6;
    const int wm   = wv >> 1;
    const int wn   = wv & 1;

    // XCD chunking (16000 % 8 == 0, bijective), nb fast within chunk.
    const int bid = blockIdx.x;
    const int wg  = (bid & 7) * 2000 + (bid >> 3);
    const int mb  = wg / 250;     // 0..63 (8 per XCD chunk)
    const int nb  = wg % 250;     // fast axis

    const int m0 = mb * 128 + wm * 64;
    const int n0 = nb * 128 + wn * 64;
    const int lr = lane & 15;
    const int kq = lane >> 4;

    const __hip_bfloat16* Arow = A  + (size_t)(m0 + lr) * HID + kq * 8;
    const __hip_bfloat16* Wrow = Wb + (size_t)(n0 + lr) * HID + kq * 8;

    for (int rep = 0; rep < 4; ++rep) {
        f32x4_t acc[4][4];
        #pragma unroll
        for (int i = 0; i < 4; ++i)
            #pragma unroll
            for (int jj = 0; jj < 4; ++jj)
                acc[i][jj] = (f32x4_t){0.f, 0.f, 0.f, 0.f};

        bf16x8_t af[2][4], bw[2][4];
        #pragma unroll
        for (int mt = 0; mt < 4; ++mt) af[0][mt] = *(const bf16x8_t*)(Arow + mt * 16 * HID);
        #pragma unroll
        for (int nt = 0; nt < 4; ++nt) bw[0][nt] = *(const bf16x8_t*)(Wrow + nt * 16 * HID);

        #pragma unroll
        for (int kk = 0; kk < 4; ++kk) {
            const int cur = kk & 1, nxt = cur ^ 1;
            if (kk < 3) {
                const int off = (kk + 1) * 32;
                #pragma unroll
                for (int mt = 0; mt < 4; ++mt)
                    af[nxt][mt] = *(const bf16x8_t*)(Arow + mt * 16 * HID + off);
                #pragma unroll
                for (int nt = 0; nt < 4; ++nt)
                    bw[nxt][nt] = *(const bf16x8_t*)(Wrow + nt * 16 * HID + off);
            }
            #pragma unroll
            for (int mt = 0; mt < 4; ++mt)
                #pragma unroll
                for (int nt = 0; nt < 4; ++nt)
                    acc[mt][nt] = __builtin_amdgcn_mfma_f32_16x16x32_bf16(
                        bw[cur][nt], af[cur][mt], acc[mt][nt], 0, 0, 0);
        }

        // D (swapped): reg axis = 4 consecutive vocab cols, lane&15 = m row.
        const int vq = kq * 4;
        #pragma unroll
        for (int nt = 0; nt < 4; ++nt) {
            const int v0 = n0 + nt * 16 + vq;
            float4 fb = *(const float4*)(fc_b + v0);
            const f32x4_t fbv = {fb.x, fb.y, fb.z, fb.w};
            #pragma unroll
            for (int mt = 0; mt < 4; ++mt) {
                const int row = m0 + mt * 16 + lr;
                *(f32x4_t*)(C + (size_t)row * VOCAB + v0) = acc[mt][nt] + fbv;
            }
        }
        asm volatile("" ::: "memory");
    }
}

// ---------------------------------------------------------------------------
extern "C" void kernel_launch(void* const* d_in, const int* in_sizes, int n_in,
                              void* d_out, int out_size, void* d_ws, size_t ws_size,
                              hipStream_t stream)
{
    const int*   x    = (const int*)  d_in[0];
    const float* emb  = (const float*)d_in[1];
    const float* W_ih = (const float*)d_in[2];
    const float* b_ih = (const float*)d_in[3];
    const float* W_hh = (const float*)d_in[4];
    const float* b_hh = (const float*)d_in[5];
    const float* fc_W = (const float*)d_in[6];
    const float* fc_b = (const float*)d_in[7];

    float* logits = (float*)d_out;
    float* hidden = logits + (size_t)BB * SS * VOCAB;

    char* ws = (char*)d_ws;
    float*           xpb = (float*)ws;                               // 4,194,304 B
    __hip_bfloat16*  hsb = (__hip_bfloat16*)(ws + 4194304);          // 2,097,152 B
    __hip_bfloat16*  fwb = (__hip_bfloat16*)(ws + 6291456);          // 8,192,000 B

    xproj_kernel<<<dim3(256), dim3(512), 0, stream>>>(x, emb, W_ih, b_ih, b_hh, xpb);
    convert_bf16_kernel<<<dim3(2000), dim3(256), 0, stream>>>(fc_W, fwb);
    rnn_kernel<<<dim3(8), dim3(512), 0, stream>>>(xpb, W_hh, hsb, hidden);
    fc_kernel<<<dim3(16000), dim3(256), 0, stream>>>(hsb, fwb, fc_b, logits);
}

// Round 6
// 781.009 us; speedup vs baseline: 3.4130x; 3.4130x over previous
//
#include <hip/hip_runtime.h>
#include <hip/hip_bf16.h>

#define VOCAB 32000
#define EMB   128
#define HID   128
#define BB    8
#define SS    1024

typedef __bf16 bf16x8_t __attribute__((ext_vector_type(8)));
typedef float  f32x4_t  __attribute__((ext_vector_type(4)));

__device__ __forceinline__ float dpp_xor1(float x) {
    return __int_as_float(__builtin_amdgcn_update_dpp(
        0, __float_as_int(x), 0xB1, 0xF, 0xF, true));   // quad_perm(1,0,3,2)
}
__device__ __forceinline__ float dpp_xor2(float x) {
    return __int_as_float(__builtin_amdgcn_update_dpp(
        0, __float_as_int(x), 0x4E, 0xF, 0xF, true));   // quad_perm(2,3,0,1)
}

// ---------------------------------------------------------------------------
// Kernel A: xp[b,s,h] = sum_e emb[x[b,s],e] * W_ih[h,e] + b_ih[h] + b_hh[h]
// ---------------------------------------------------------------------------
__global__ __launch_bounds__(512) void xproj_kernel(
    const int* __restrict__ x, const float* __restrict__ emb,
    const float* __restrict__ W_ih, const float* __restrict__ b_ih,
    const float* __restrict__ b_hh, float* __restrict__ xp)
{
    const int t  = threadIdx.x;
    const int h  = t >> 2;
    const int ks = t & 3;

    float w[32];
    {
        const float* wr = W_ih + h * EMB + ks * 32;
        #pragma unroll
        for (int i = 0; i < 32; i += 4) {
            float4 v = *(const float4*)(wr + i);
            w[i] = v.x; w[i+1] = v.y; w[i+2] = v.z; w[i+3] = v.w;
        }
    }
    const float bias = b_ih[h] + b_hh[h];

    __shared__ float el[2][EMB];
    const int base = blockIdx.x * 32;

    float4 v = make_float4(0.f, 0.f, 0.f, 0.f);
    if (t < 32) v = *(const float4*)(emb + (size_t)x[base] * EMB + t * 4);

    for (int r = 0; r < 32; ++r) {
        if (t < 32) *(float4*)(&el[r & 1][t * 4]) = v;
        __syncthreads();
        if (t < 32 && r + 1 < 32)
            v = *(const float4*)(emb + (size_t)x[base + r + 1] * EMB + t * 4);

        float a0 = 0.f, a1 = 0.f, a2 = 0.f, a3 = 0.f;
        const float* e = &el[r & 1][ks * 32];
        #pragma unroll
        for (int c = 0; c < 8; ++c) {
            float4 hv = *(const float4*)(e + c * 4);
            a0 = fmaf(w[c*4+0], hv.x, a0);
            a1 = fmaf(w[c*4+1], hv.y, a1);
            a2 = fmaf(w[c*4+2], hv.z, a2);
            a3 = fmaf(w[c*4+3], hv.w, a3);
        }
        float sum = (a0 + a1) + (a2 + a3);
        sum += __shfl_xor(sum, 1);
        sum += __shfl_xor(sum, 2);
        if (ks == 0) xp[(size_t)(base + r) * HID + h] = bias + sum;
    }
}

// ---------------------------------------------------------------------------
// Kernel D: fp32 -> bf16 convert for fc_W
// ---------------------------------------------------------------------------
__global__ __launch_bounds__(256) void convert_bf16_kernel(
    const float* __restrict__ in, __hip_bfloat16* __restrict__ out)
{
    const size_t i = ((size_t)blockIdx.x * 256 + threadIdx.x) * 8;
    float4 a = *(const float4*)(in + i);
    float4 b = *(const float4*)(in + i + 4);
    union { __hip_bfloat16 h[8]; uint4 u; } p;
    p.h[0] = __float2bfloat16(a.x); p.h[1] = __float2bfloat16(a.y);
    p.h[2] = __float2bfloat16(a.z); p.h[3] = __float2bfloat16(a.w);
    p.h[4] = __float2bfloat16(b.x); p.h[5] = __float2bfloat16(b.y);
    p.h[6] = __float2bfloat16(b.z); p.h[7] = __float2bfloat16(b.w);
    *(uint4*)(out + i) = p.u;
}

// ---------------------------------------------------------------------------
// Kernel B: recurrence, rebuilt per R5 counters.
// 8 blocks x 256 threads (4 waves). lane: ks = l&3 (32-float K-slice),
// g = l>>2; rows jb = w*16+g and jb+64 (W slice = 64 VGPR).
// h in LDS with padded layout word(k) = k + (k>>4)*4  -> ks-slices start at
// banks {0,8,16,24}: zero conflicts. K-reduction = 2 DPP quad-perm ops
// (VALU) instead of LDS shuffles. One barrier per step.
// ---------------------------------------------------------------------------
__global__ __launch_bounds__(256) void rnn_kernel(
    const float* __restrict__ xp, const float* __restrict__ W_hh,
    __hip_bfloat16* __restrict__ hs_bf16, float* __restrict__ hidden_out)
{
    const int b  = blockIdx.x;
    const int t  = threadIdx.x;
    const int w  = t >> 6;
    const int l  = t & 63;
    const int ks = l & 3;
    const int g  = l >> 2;
    const int jb = w * 16 + g;           // 0..63

    f32x4_t wr[2][8];
    #pragma unroll
    for (int m = 0; m < 2; ++m) {
        const float* src = W_hh + (size_t)(jb + 64 * m) * HID + ks * 32;
        #pragma unroll
        for (int i = 0; i < 8; ++i) wr[m][i] = *(const f32x4_t*)(src + i * 4);
    }

    __shared__ float hbuf[2][160];        // padded: word(k) = k + (k>>4)*4
    if (t < 160) hbuf[0][t] = 0.f;

    const float* xpb = xp + (size_t)b * SS * HID;
    const bool  wrt  = (ks == 0);
    float p0[2], p1[2];
    if (wrt) {
        #pragma unroll
        for (int m = 0; m < 2; ++m) {
            p0[m] = xpb[jb + 64 * m];
            p1[m] = xpb[HID + jb + 64 * m];
        }
    }
    __syncthreads();

    const int rbase = ks * 40;            // k = ks*32 -> word ks*40
    for (int step = 0; step < SS; ++step) {
        const float* hc = hbuf[step & 1];
        f32x4_t hv[8];
        #pragma unroll
        for (int i = 0; i < 4; ++i)
            hv[i] = *(const f32x4_t*)(hc + rbase + i * 4);
        #pragma unroll
        for (int i = 4; i < 8; ++i)
            hv[i] = *(const f32x4_t*)(hc + rbase + 4 + i * 4);   // +4 pad skip

        f32x4_t a0 = {0.f,0.f,0.f,0.f}, a1 = a0, c0 = a0, c1 = a0;
        #pragma unroll
        for (int i = 0; i < 4; ++i) {
            a0 += wr[0][i] * hv[i];
            a1 += wr[0][i+4] * hv[i+4];
            c0 += wr[1][i] * hv[i];
            c1 += wr[1][i+4] * hv[i+4];
        }
        f32x4_t av = a0 + a1, cv = c0 + c1;
        float s0 = (av.x + av.y) + (av.z + av.w);
        float s1 = (cv.x + cv.y) + (cv.z + cv.w);

        s0 += dpp_xor1(s0);  s0 += dpp_xor2(s0);
        s1 += dpp_xor1(s1);  s1 += dpp_xor2(s1);

        if (wrt) {
            float sm[2] = {s0, s1};
            #pragma unroll
            for (int m = 0; m < 2; ++m) {
                const float z  = p0[m] + sm[m];
                const float e  = __expf(2.0f * z);
                const float hn = 1.0f - 2.0f * __builtin_amdgcn_rcpf(e + 1.0f);
                const int   j  = jb + 64 * m;
                hbuf[(step + 1) & 1][j + ((j >> 4) << 2)] = hn;
                hs_bf16[((size_t)b * SS + step) * HID + j] = __float2bfloat16(hn);
                if (step == SS - 1) hidden_out[b * HID + j] = hn;
                p0[m] = p1[m];
            }
            if (step + 2 < SS) {
                #pragma unroll
                for (int m = 0; m < 2; ++m)
                    p1[m] = xpb[(size_t)(step + 2) * HID + jb + 64 * m];
            }
        }
        __syncthreads();
    }
}

// ---------------------------------------------------------------------------
// Kernel C: logits = A @ Wb^T + fc_b. (R5 config: swapped-operand MFMA ->
// float4 stores, NORMAL stores via L2, XCD-chunked swizzle nb-fast.)
// Measured ~185-230 us — at the HBM write floor.
// ---------------------------------------------------------------------------
__global__ __launch_bounds__(256) void fc_kernel(
    const __hip_bfloat16* __restrict__ A, const __hip_bfloat16* __restrict__ Wb,
    const float* __restrict__ fc_b, float* __restrict__ C)
{
    const int lane = threadIdx.x & 63;
    const int wv   = threadIdx.x >> 6;
    const int wm   = wv >> 1;
    const int wn   = wv & 1;

    const int bid = blockIdx.x;
    const int wg  = (bid & 7) * 2000 + (bid >> 3);
    const int mb  = wg / 250;
    const int nb  = wg % 250;

    const int m0 = mb * 128 + wm * 64;
    const int n0 = nb * 128 + wn * 64;
    const int lr = lane & 15;
    const int kq = lane >> 4;

    const __hip_bfloat16* Arow = A  + (size_t)(m0 + lr) * HID + kq * 8;
    const __hip_bfloat16* Wrow = Wb + (size_t)(n0 + lr) * HID + kq * 8;

    f32x4_t acc[4][4];
    #pragma unroll
    for (int i = 0; i < 4; ++i)
        #pragma unroll
        for (int jj = 0; jj < 4; ++jj)
            acc[i][jj] = (f32x4_t){0.f, 0.f, 0.f, 0.f};

    bf16x8_t af[2][4], bw[2][4];
    #pragma unroll
    for (int mt = 0; mt < 4; ++mt) af[0][mt] = *(const bf16x8_t*)(Arow + mt * 16 * HID);
    #pragma unroll
    for (int nt = 0; nt < 4; ++nt) bw[0][nt] = *(const bf16x8_t*)(Wrow + nt * 16 * HID);

    #pragma unroll
    for (int kk = 0; kk < 4; ++kk) {
        const int cur = kk & 1, nxt = cur ^ 1;
        if (kk < 3) {
            const int off = (kk + 1) * 32;
            #pragma unroll
            for (int mt = 0; mt < 4; ++mt)
                af[nxt][mt] = *(const bf16x8_t*)(Arow + mt * 16 * HID + off);
            #pragma unroll
            for (int nt = 0; nt < 4; ++nt)
                bw[nxt][nt] = *(const bf16x8_t*)(Wrow + nt * 16 * HID + off);
        }
        #pragma unroll
        for (int mt = 0; mt < 4; ++mt)
            #pragma unroll
            for (int nt = 0; nt < 4; ++nt)
                acc[mt][nt] = __builtin_amdgcn_mfma_f32_16x16x32_bf16(
                    bw[cur][nt], af[cur][mt], acc[mt][nt], 0, 0, 0);
    }

    const int vq = kq * 4;
    #pragma unroll
    for (int nt = 0; nt < 4; ++nt) {
        const int v0 = n0 + nt * 16 + vq;
        float4 fb = *(const float4*)(fc_b + v0);
        const f32x4_t fbv = {fb.x, fb.y, fb.z, fb.w};
        #pragma unroll
        for (int mt = 0; mt < 4; ++mt) {
            const int row = m0 + mt * 16 + lr;
            *(f32x4_t*)(C + (size_t)row * VOCAB + v0) = acc[mt][nt] + fbv;
        }
    }
}

// ---------------------------------------------------------------------------
extern "C" void kernel_launch(void* const* d_in, const int* in_sizes, int n_in,
                              void* d_out, int out_size, void* d_ws, size_t ws_size,
                              hipStream_t stream)
{
    const int*   x    = (const int*)  d_in[0];
    const float* emb  = (const float*)d_in[1];
    const float* W_ih = (const float*)d_in[2];
    const float* b_ih = (const float*)d_in[3];
    const float* W_hh = (const float*)d_in[4];
    const float* b_hh = (const float*)d_in[5];
    const float* fc_W = (const float*)d_in[6];
    const float* fc_b = (const float*)d_in[7];

    float* logits = (float*)d_out;
    float* hidden = logits + (size_t)BB * SS * VOCAB;

    char* ws = (char*)d_ws;
    float*           xpb = (float*)ws;                               // 4,194,304 B
    __hip_bfloat16*  hsb = (__hip_bfloat16*)(ws + 4194304);          // 2,097,152 B
    __hip_bfloat16*  fwb = (__hip_bfloat16*)(ws + 6291456);          // 8,192,000 B

    xproj_kernel<<<dim3(256), dim3(512), 0, stream>>>(x, emb, W_ih, b_ih, b_hh, xpb);
    convert_bf16_kernel<<<dim3(2000), dim3(256), 0, stream>>>(fc_W, fwb);
    rnn_kernel<<<dim3(8), dim3(256), 0, stream>>>(xpb, W_hh, hsb, hidden);
    fc_kernel<<<dim3(16000), dim3(256), 0, stream>>>(hsb, fwb, fc_b, logits);
}

// Round 7
// 652.618 us; speedup vs baseline: 4.0845x; 1.1967x over previous
//
#include <hip/hip_runtime.h>
#include <hip/hip_bf16.h>

#define VOCAB 32000
#define EMB   128
#define HID   128
#define BB    8
#define SS    1024

typedef __bf16 bf16x8_t __attribute__((ext_vector_type(8)));
typedef float  f32x4_t  __attribute__((ext_vector_type(4)));

__device__ __forceinline__ float dpp_xor1(float x) {
    return __int_as_float(__builtin_amdgcn_update_dpp(
        0, __float_as_int(x), 0xB1, 0xF, 0xF, true));   // quad_perm(1,0,3,2)
}
__device__ __forceinline__ float dpp_xor2(float x) {
    return __int_as_float(__builtin_amdgcn_update_dpp(
        0, __float_as_int(x), 0x4E, 0xF, 0xF, true));   // quad_perm(2,3,0,1)
}

// ---------------------------------------------------------------------------
// Kernel A: xp[b,s,h] = sum_e emb[x[b,s],e] * W_ih[h,e] + b_ih[h] + b_hh[h]
// ---------------------------------------------------------------------------
__global__ __launch_bounds__(512) void xproj_kernel(
    const int* __restrict__ x, const float* __restrict__ emb,
    const float* __restrict__ W_ih, const float* __restrict__ b_ih,
    const float* __restrict__ b_hh, float* __restrict__ xp)
{
    const int t  = threadIdx.x;
    const int h  = t >> 2;
    const int ks = t & 3;

    float w[32];
    {
        const float* wr = W_ih + h * EMB + ks * 32;
        #pragma unroll
        for (int i = 0; i < 32; i += 4) {
            float4 v = *(const float4*)(wr + i);
            w[i] = v.x; w[i+1] = v.y; w[i+2] = v.z; w[i+3] = v.w;
        }
    }
    const float bias = b_ih[h] + b_hh[h];

    __shared__ float el[2][EMB];
    const int base = blockIdx.x * 32;

    float4 v = make_float4(0.f, 0.f, 0.f, 0.f);
    if (t < 32) v = *(const float4*)(emb + (size_t)x[base] * EMB + t * 4);

    for (int r = 0; r < 32; ++r) {
        if (t < 32) *(float4*)(&el[r & 1][t * 4]) = v;
        __syncthreads();
        if (t < 32 && r + 1 < 32)
            v = *(const float4*)(emb + (size_t)x[base + r + 1] * EMB + t * 4);

        float a0 = 0.f, a1 = 0.f, a2 = 0.f, a3 = 0.f;
        const float* e = &el[r & 1][ks * 32];
        #pragma unroll
        for (int c = 0; c < 8; ++c) {
            float4 hv = *(const float4*)(e + c * 4);
            a0 = fmaf(w[c*4+0], hv.x, a0);
            a1 = fmaf(w[c*4+1], hv.y, a1);
            a2 = fmaf(w[c*4+2], hv.z, a2);
            a3 = fmaf(w[c*4+3], hv.w, a3);
        }
        float sum = (a0 + a1) + (a2 + a3);
        sum += __shfl_xor(sum, 1);
        sum += __shfl_xor(sum, 2);
        if (ks == 0) xp[(size_t)(base + r) * HID + h] = bias + sum;
    }
}

// ---------------------------------------------------------------------------
// Kernel D: fp32 -> bf16 convert for fc_W
// ---------------------------------------------------------------------------
__global__ __launch_bounds__(256) void convert_bf16_kernel(
    const float* __restrict__ in, __hip_bfloat16* __restrict__ out)
{
    const size_t i = ((size_t)blockIdx.x * 256 + threadIdx.x) * 8;
    float4 a = *(const float4*)(in + i);
    float4 b = *(const float4*)(in + i + 4);
    union { __hip_bfloat16 h[8]; uint4 u; } p;
    p.h[0] = __float2bfloat16(a.x); p.h[1] = __float2bfloat16(a.y);
    p.h[2] = __float2bfloat16(a.z); p.h[3] = __float2bfloat16(a.w);
    p.h[4] = __float2bfloat16(b.x); p.h[5] = __float2bfloat16(b.y);
    p.h[6] = __float2bfloat16(b.z); p.h[7] = __float2bfloat16(b.w);
    *(uint4*)(out + i) = p.u;
}

// ---------------------------------------------------------------------------
// Kernel B: recurrence. 8 blocks x 256 threads (4 waves).
// R6 structure (broadcast LDS reads, padded banks, DPP reduce) PLUS:
//  - raw s_barrier with only lgkmcnt(0): global ops are NOT drained at the
//    per-step barrier (removes the ~700cyc/step vmcnt(0) drain of
//    __syncthreads).
//  - xp prefetched a full 8-step superstep ahead into ping-ponged STATIC
//    register files xsA/xsB (no dynamic indexing -> no scratch).
// ---------------------------------------------------------------------------
__global__ __launch_bounds__(256) void rnn_kernel(
    const float* __restrict__ xp, const float* __restrict__ W_hh,
    __hip_bfloat16* __restrict__ hs_bf16, float* __restrict__ hidden_out)
{
    const int b  = blockIdx.x;
    const int t  = threadIdx.x;
    const int w  = t >> 6;
    const int l  = t & 63;
    const int ks = l & 3;
    const int g  = l >> 2;
    const int jb = w * 16 + g;           // 0..63

    f32x4_t wr[2][8];
    #pragma unroll
    for (int m = 0; m < 2; ++m) {
        const float* src = W_hh + (size_t)(jb + 64 * m) * HID + ks * 32;
        #pragma unroll
        for (int i = 0; i < 8; ++i) wr[m][i] = *(const f32x4_t*)(src + i * 4);
    }

    __shared__ float hbuf[2][160];        // padded: word(k) = k + (k>>4)*4
    if (t < 160) hbuf[0][t] = 0.f;

    const float* xpb = xp + (size_t)b * SS * HID;
    const bool  wrt  = (ks == 0);

    float xsA[8][2], xsB[8][2];
    if (wrt) {
        #pragma unroll
        for (int u = 0; u < 8; ++u) {
            xsA[u][0] = xpb[(size_t)u * HID + jb];
            xsA[u][1] = xpb[(size_t)u * HID + jb + 64];
        }
    }
    __syncthreads();   // once: initial h + xsA visible

    const int rbase = ks * 40;            // k = ks*32 -> word ks*40

#define RNN_SUPERSTEP(XC, XN, BASE)                                          \
    {                                                                        \
        const int nbase_ = (BASE) + 8;                                       \
        if (wrt && nbase_ < SS) {                                            \
            _Pragma("unroll")                                                \
            for (int u = 0; u < 8; ++u) {                                    \
                XN[u][0] = xpb[(size_t)(nbase_ + u) * HID + jb];             \
                XN[u][1] = xpb[(size_t)(nbase_ + u) * HID + jb + 64];        \
            }                                                                \
        }                                                                    \
        _Pragma("unroll")                                                    \
        for (int u = 0; u < 8; ++u) {                                        \
            const int step_ = (BASE) + u;                                    \
            const float* hc_ = hbuf[u & 1];                                  \
            f32x4_t hv[8];                                                   \
            _Pragma("unroll")                                                \
            for (int i = 0; i < 4; ++i)                                      \
                hv[i] = *(const f32x4_t*)(hc_ + rbase + i * 4);              \
            _Pragma("unroll")                                                \
            for (int i = 4; i < 8; ++i)                                      \
                hv[i] = *(const f32x4_t*)(hc_ + rbase + 4 + i * 4);          \
            f32x4_t a0 = {0.f,0.f,0.f,0.f}, a1 = a0, c0 = a0, c1 = a0;       \
            _Pragma("unroll")                                                \
            for (int i = 0; i < 4; ++i) {                                    \
                a0 += wr[0][i]   * hv[i];                                    \
                a1 += wr[0][i+4] * hv[i+4];                                  \
                c0 += wr[1][i]   * hv[i];                                    \
                c1 += wr[1][i+4] * hv[i+4];                                  \
            }                                                                \
            f32x4_t av = a0 + a1, cv = c0 + c1;                              \
            float s0 = (av.x + av.y) + (av.z + av.w);                        \
            float s1 = (cv.x + cv.y) + (cv.z + cv.w);                        \
            s0 += dpp_xor1(s0);  s0 += dpp_xor2(s0);                         \
            s1 += dpp_xor1(s1);  s1 += dpp_xor2(s1);                         \
            if (wrt) {                                                       \
                const float z0 = XC[u][0] + s0;                              \
                const float e0 = __expf(2.0f * z0);                          \
                const float h0 = 1.0f - 2.0f * __builtin_amdgcn_rcpf(e0 + 1.0f); \
                const float z1 = XC[u][1] + s1;                              \
                const float e1 = __expf(2.0f * z1);                          \
                const float h1 = 1.0f - 2.0f * __builtin_amdgcn_rcpf(e1 + 1.0f); \
                const int j0 = jb, j1 = jb + 64;                             \
                hbuf[(u + 1) & 1][j0 + ((j0 >> 4) << 2)] = h0;               \
                hbuf[(u + 1) & 1][j1 + ((j1 >> 4) << 2)] = h1;               \
                hs_bf16[((size_t)b * SS + step_) * HID + j0] = __float2bfloat16(h0); \
                hs_bf16[((size_t)b * SS + step_) * HID + j1] = __float2bfloat16(h1); \
                if (step_ == SS - 1) {                                       \
                    hidden_out[b * HID + j0] = h0;                           \
                    hidden_out[b * HID + j1] = h1;                           \
                }                                                            \
            }                                                                \
            asm volatile("s_waitcnt lgkmcnt(0)" ::: "memory");               \
            __builtin_amdgcn_s_barrier();                                    \
        }                                                                    \
    }

    for (int sb2 = 0; sb2 < SS / 16; ++sb2) {
        const int base = sb2 * 16;
        RNN_SUPERSTEP(xsA, xsB, base);
        RNN_SUPERSTEP(xsB, xsA, base + 8);
    }
#undef RNN_SUPERSTEP
}

// ---------------------------------------------------------------------------
// Kernel C: logits = A @ Wb^T + fc_b. (R5-validated config: swapped-operand
// MFMA -> float4 stores, normal stores via L2, XCD-chunked swizzle nb-fast.)
// Measured ~185-230 us — at the HBM write floor.
// ---------------------------------------------------------------------------
__global__ __launch_bounds__(256) void fc_kernel(
    const __hip_bfloat16* __restrict__ A, const __hip_bfloat16* __restrict__ Wb,
    const float* __restrict__ fc_b, float* __restrict__ C)
{
    const int lane = threadIdx.x & 63;
    const int wv   = threadIdx.x >> 6;
    const int wm   = wv >> 1;
    const int wn   = wv & 1;

    const int bid = blockIdx.x;
    const int wg  = (bid & 7) * 2000 + (bid >> 3);
    const int mb  = wg / 250;
    const int nb  = wg % 250;

    const int m0 = mb * 128 + wm * 64;
    const int n0 = nb * 128 + wn * 64;
    const int lr = lane & 15;
    const int kq = lane >> 4;

    const __hip_bfloat16* Arow = A  + (size_t)(m0 + lr) * HID + kq * 8;
    const __hip_bfloat16* Wrow = Wb + (size_t)(n0 + lr) * HID + kq * 8;

    f32x4_t acc[4][4];
    #pragma unroll
    for (int i = 0; i < 4; ++i)
        #pragma unroll
        for (int jj = 0; jj < 4; ++jj)
            acc[i][jj] = (f32x4_t){0.f, 0.f, 0.f, 0.f};

    bf16x8_t af[2][4], bw[2][4];
    #pragma unroll
    for (int mt = 0; mt < 4; ++mt) af[0][mt] = *(const bf16x8_t*)(Arow + mt * 16 * HID);
    #pragma unroll
    for (int nt = 0; nt < 4; ++nt) bw[0][nt] = *(const bf16x8_t*)(Wrow + nt * 16 * HID);

    #pragma unroll
    for (int kk = 0; kk < 4; ++kk) {
        const int cur = kk & 1, nxt = cur ^ 1;
        if (kk < 3) {
            const int off = (kk + 1) * 32;
            #pragma unroll
            for (int mt = 0; mt < 4; ++mt)
                af[nxt][mt] = *(const bf16x8_t*)(Arow + mt * 16 * HID + off);
            #pragma unroll
            for (int nt = 0; nt < 4; ++nt)
                bw[nxt][nt] = *(const bf16x8_t*)(Wrow + nt * 16 * HID + off);
        }
        #pragma unroll
        for (int mt = 0; mt < 4; ++mt)
            #pragma unroll
            for (int nt = 0; nt < 4; ++nt)
                acc[mt][nt] = __builtin_amdgcn_mfma_f32_16x16x32_bf16(
                    bw[cur][nt], af[cur][mt], acc[mt][nt], 0, 0, 0);
    }

    const int vq = kq * 4;
    #pragma unroll
    for (int nt = 0; nt < 4; ++nt) {
        const int v0 = n0 + nt * 16 + vq;
        float4 fb = *(const float4*)(fc_b + v0);
        const f32x4_t fbv = {fb.x, fb.y, fb.z, fb.w};
        #pragma unroll
        for (int mt = 0; mt < 4; ++mt) {
            const int row = m0 + mt * 16 + lr;
            *(f32x4_t*)(C + (size_t)row * VOCAB + v0) = acc[mt][nt] + fbv;
        }
    }
}

// ---------------------------------------------------------------------------
extern "C" void kernel_launch(void* const* d_in, const int* in_sizes, int n_in,
                              void* d_out, int out_size, void* d_ws, size_t ws_size,
                              hipStream_t stream)
{
    const int*   x    = (const int*)  d_in[0];
    const float* emb  = (const float*)d_in[1];
    const float* W_ih = (const float*)d_in[2];
    const float* b_ih = (const float*)d_in[3];
    const float* W_hh = (const float*)d_in[4];
    const float* b_hh = (const float*)d_in[5];
    const float* fc_W = (const float*)d_in[6];
    const float* fc_b = (const float*)d_in[7];

    float* logits = (float*)d_out;
    float* hidden = logits + (size_t)BB * SS * VOCAB;

    char* ws = (char*)d_ws;
    float*           xpb = (float*)ws;                               // 4,194,304 B
    __hip_bfloat16*  hsb = (__hip_bfloat16*)(ws + 4194304);          // 2,097,152 B
    __hip_bfloat16*  fwb = (__hip_bfloat16*)(ws + 6291456);          // 8,192,000 B

    xproj_kernel<<<dim3(256), dim3(512), 0, stream>>>(x, emb, W_ih, b_ih, b_hh, xpb);
    convert_bf16_kernel<<<dim3(2000), dim3(256), 0, stream>>>(fc_W, fwb);
    rnn_kernel<<<dim3(8), dim3(256), 0, stream>>>(xpb, W_hh, hsb, hidden);
    fc_kernel<<<dim3(16000), dim3(256), 0, stream>>>(hsb, fwb, fc_b, logits);
}